// Round 3
// baseline (144.643 us; speedup 1.0000x reference)
//
#include <hip/hip_runtime.h>
#include <stdint.h>

// MS-SSIM + L1 fused loss, MI355X.
// R14: occupancy push. R13 counters: no pipe >50% (VALU 48, LDS ~57, MFMA 15),
// occupancy stuck ~19.5% -> latency/barrier-bound, LDS is the binder.
// Changes:
//  1. PT aliases XQ in one 23KB region (they are never simultaneously live:
//     XQ is only read by load_derive, once per channel, after which all conv
//     passes touch only PT). LDS 47.1KB -> ~28.5KB -> 4 blocks/CU (VGPR-bound).
//     +4 barriers to order region reuse.
//  2. V-pass weight frags are identical to W.h[wave>>1] (same lane addresses)
//     -> wave-uniform ternary select instead of 2 ds_read_b128 per pass.
//  3. SAD plane placed at region+PTPLN so conv_pass<1>'s PT plane-0 writes
//     don't clobber it.
// Everything else identical to R13 (numerically verified).

#define TILE 32
#define HALO 16
#define SSTR 72            // bf16 stride (144B row, 16B-multiple)
#define PLN  (64 * SSTR)
#define PTPLN (32 * SSTR)
#define NT   256

#define C1c 1.0e-4f
#define C2c 9.0e-4f

typedef short bf16x8 __attribute__((ext_vector_type(8)));
typedef float f32x4  __attribute__((ext_vector_type(4)));
typedef unsigned short ush;

// ---- compile-time 1/sum of the 33-tap gaussian ----
constexpr double cexp(double xx) {
  if (xx < -700.0) return 0.0;
  const double ln2 = 0.6931471805599453, il2 = 1.4426950408889634;
  double kd = xx * il2;
  long long k = (long long)(kd + (kd >= 0 ? 0.5 : -0.5));
  double r = xx - (double)k * ln2;
  double t = 1.0, s = 1.0;
  for (int i = 1; i <= 22; ++i) { t *= r / (double)i; s += t; }
  double p = 1.0, base = (k >= 0) ? 2.0 : 0.5;
  long long n = (k >= 0) ? k : -k;
  while (n) { if (n & 1) p *= base; base *= base; n >>= 1; }
  return s * p;
}
constexpr float gsi(double sigma) {
  double inv = 1.0 / (2.0 * sigma * sigma);
  double s = 0.0;
  for (int k = -16; k <= 16; ++k) s += cexp(-(double)(k * k) * inv);
  return (float)(1.0 / s);
}
constexpr float SI05 = gsi(0.5), SI10 = gsi(1.0), SI20 = gsi(2.0),
                SI40 = gsi(4.0), SI80 = gsi(8.0);

// pack two f32 -> bf16x2 (round-half-up)
__device__ __forceinline__ unsigned f2bf_pk(float lo, float hi) {
  union { float f; unsigned u; } a, b; a.f = lo; b.f = hi;
  return __builtin_amdgcn_perm(b.u + 0x8000u, a.u + 0x8000u, 0x07060302u);
}
__device__ __forceinline__ ush f2bf1(float f) {
  union { float f; unsigned u; } c; c.f = f;
  return (ush)((c.u + 0x8000u) >> 16);
}

struct WFrag {
  bf16x8 h[2][2];   // [nt][kchunk] : H-pass B-operand; V-pass A-operand is h[wave>>1]
};

// Fill WM[m][k] = wf5[SIG][k-m] (k-m in [0,32] else 0), then load H frags.
template<int SIG>
__device__ __forceinline__ void build_wm(ush* __restrict__ WM,
                                         const float (*__restrict__ wf5)[40],
                                         int tid, int wave, int lane,
                                         WFrag& W) {
  __syncthreads();                 // prior frag/PT/XQ readers ordered before WM writes & later PT stores
  #pragma unroll
  for (int i = 0; i < 8; ++i) {
    const int idx = i * 256 + tid;         // 0..2047
    const int m = idx >> 6, k = idx & 63;
    const int t = k - m;
    const int tc = t < 0 ? 0 : (t > 32 ? 32 : t);
    float v = wf5[SIG][tc];
    v = (t >= 0 && t <= 32) ? v : 0.f;
    WM[m * SSTR + k] = f2bf1(v);
  }
  __syncthreads();                 // WM ready
  const int l16 = lane & 15, quad = lane >> 4;
  #pragma unroll
  for (int t = 0; t < 2; ++t)
    #pragma unroll
    for (int c = 0; c < 2; ++c)
      W.h[t][c] = *(const bf16x8*)(WM + (t * 16 + l16) * SSTR + quad * 8 + 32 * c);
}

// One separable conv pass via two banded GEMMs; A-fragments and all weights
// from registers (V weights = W.h[wave>>1], wave-uniform select).
// Caller must ensure a barrier ordered prior PT/region readers before entry.
template<int NQ>
__device__ __forceinline__ void conv_pass(const bf16x8 (&A)[NQ][2],
                                          const WFrag& W,
                                          ush* __restrict__ PT,
                                          int wave, int lane, f32x4* V) {
  const int l16 = lane & 15, quad = lane >> 4;
  const int m0 = wave * 16;
  // H-GEMM: D(64x32) = A(64x64) x Wh; store transposed bf16 into PT
  #pragma unroll
  for (int q = 0; q < NQ; ++q) {
    #pragma unroll
    for (int nt = 0; nt < 2; ++nt) {
      f32x4 acc = {0.f, 0.f, 0.f, 0.f};
      acc = __builtin_amdgcn_mfma_f32_16x16x32_bf16(A[q][0], W.h[nt][0], acc, 0, 0, 0);
      acc = __builtin_amdgcn_mfma_f32_16x16x32_bf16(A[q][1], W.h[nt][1], acc, 0, 0, 0);
      uint2 u;
      u.x = f2bf_pk(acc[0], acc[1]);
      u.y = f2bf_pk(acc[2], acc[3]);
      *(uint2*)(PT + q * PTPLN + (nt * 16 + l16) * SSTR + m0 + quad * 4) = u;
    }
  }
  // V-pass A-operand: identical lane addressing to W.h[wave>>1] (wave-uniform)
  const bf16x8 wv0 = (wave & 2) ? W.h[1][0] : W.h[0][0];
  const bf16x8 wv1 = (wave & 2) ? W.h[1][1] : W.h[0][1];
  __syncthreads();                 // PT complete
  // V-GEMM: D(32x32) = Wv(32x64) x P
  const int n0 = (wave & 1) * 16;
  #pragma unroll
  for (int q = 0; q < NQ; ++q) {
    const ush* pp = PT + q * PTPLN + (n0 + l16) * SSTR + quad * 8;
    const bf16x8 b0 = *(const bf16x8*)pp;
    const bf16x8 b1 = *(const bf16x8*)(pp + 32);
    f32x4 acc = {0.f, 0.f, 0.f, 0.f};
    acc = __builtin_amdgcn_mfma_f32_16x16x32_bf16(wv0, b0, acc, 0, 0, 0);
    acc = __builtin_amdgcn_mfma_f32_16x16x32_bf16(wv1, b1, acc, 0, 0, 0);
    V[q] = acc;
  }
}

// SSIM epilogue on V[5]
__device__ __forceinline__ void ssim_fold(const f32x4* V, int mult, bool last,
                                          float* PIcs) {
  #pragma unroll
  for (int r = 0; r < 4; ++r) {
    const float mux = V[0][r], muy = V[1][r];
    const float A = mux * muy;
    const float Bq = mux * mux + muy * muy;
    const float S = V[2][r] + V[3][r] - Bq;
    const float sxy = V[4][r] - A;
    const float cs = (2.f * sxy + C2c) * __builtin_amdgcn_rcpf(S + C2c);
    float p = cs;
    if (mult >= 2) p *= cs;
    if (mult >= 3) p *= cs;
    if (last) {
      const float l = (2.f * A + C1c) * __builtin_amdgcn_rcpf(Bq + C1c);
      p *= l * l * l;
    }
    PIcs[r] *= p;
  }
}

__global__ __launch_bounds__(NT)
void msssim_fused_kernel(const float* __restrict__ x, const float* __restrict__ y,
                         const float* __restrict__ disc,
                         float* __restrict__ partials) {
  // One region aliases XQ (2 x 64-row planes) and PT (5 x 32-row planes):
  // XQ is dead once load_derive has captured the A-frags in registers.
  __shared__ ush REGION[5 * PTPLN];     // 11520 ush = 23040 B
  __shared__ ush WM[32 * SSTR];
  __shared__ float wf5[5][40];
  __shared__ float red[12];

  ush* const XQ  = REGION;              // planes x (0..PLN), y (PLN..2*PLN)
  ush* const PTB = REGION;              // 5 PT planes
  ush* const SADP = REGION + PTPLN;     // SAD plane (64 rows) for final conv;
                                        // disjoint from conv_pass<1>'s PT plane 0

  const int tid = threadIdx.x;
  const int wave = tid >> 6, lane = tid & 63;
  const int bx = blockIdx.x, by = blockIdx.y, b = blockIdx.z;
  const int x0 = bx * TILE - HALO, y0 = by * TILE - HALO;
  const int blk = (b * 16 + by) * 16 + bx;

  // disc^2 partial (16 elems/block), issued early so latency hides
  float d2 = 0.f;
  { const int di = blk * 16 + tid;
    if (tid < 16 && di < 8 * 62 * 62) { const float dd = disc[di] - 1.f; d2 = dd * dd; } }

  // one-time tap tables (first build_wm's leading barrier orders readers)
  if (tid < 165) {
    const int sig = tid / 33;
    const int k = tid - sig * 33;
    const float d = (float)(k - 16);
    float inv, si;
    if (sig == 0)      { inv = 2.0f;       si = SI05; }
    else if (sig == 1) { inv = 0.5f;       si = SI10; }
    else if (sig == 2) { inv = 0.125f;     si = SI20; }
    else if (sig == 3) { inv = 0.03125f;   si = SI40; }
    else               { inv = 0.0078125f; si = SI80; }
    wf5[sig][k] = __expf(-d * d * inv) * si;
  }

  const int sr = tid >> 4;           // staging row within 16-row band
  const int sc = (tid & 15) * 4;     // staging col group

  float4 PX[4], PY[4];
  auto issue_loads = [&](int ch) {
    const float* __restrict__ xs = x + (size_t)(b * 3 + ch) * 262144;
    const float* __restrict__ ys = y + (size_t)(b * 3 + ch) * 262144;
    #pragma unroll
    for (int it = 0; it < 4; ++it) {
      const int r = it * 16 + sr;
      const int gy = y0 + r, gx = x0 + sc;
      const bool rowok = (gy >= 0) && (gy < 512);
      if (rowok && gx >= 0 && gx <= 508) {
        PX[it] = *(const float4*)(xs + gy * 512 + gx);
        PY[it] = *(const float4*)(ys + gy * 512 + gx);
      } else {
        float tx[4], ty[4];
        #pragma unroll
        for (int e = 0; e < 4; ++e) {
          const int g = gx + e;
          const bool ok = rowok && (g >= 0) && (g < 512);
          tx[e] = ok ? xs[gy * 512 + g] : 0.f;
          ty[e] = ok ? ys[gy * 512 + g] : 0.f;
        }
        PX[it] = make_float4(tx[0], tx[1], tx[2], tx[3]);
        PY[it] = make_float4(ty[0], ty[1], ty[2], ty[3]);
      }
    }
  };

  float PIcs[4] = {1.f, 1.f, 1.f, 1.f};
  float sad[4][4];                    // sum over channels of |x-y|, 16 px/thread
  #pragma unroll
  for (int it = 0; it < 4; ++it)
    #pragma unroll
    for (int e = 0; e < 4; ++e) sad[it][e] = 0.f;

  issue_loads(0);

  // ---- staging helper: 2 planes (x, y) + SAD accumulation ----
  auto stage = [&]() {
    #pragma unroll
    for (int it = 0; it < 4; ++it) {
      const int r = it * 16 + sr;
      float xv[4] = {PX[it].x, PX[it].y, PX[it].z, PX[it].w};
      float yv[4] = {PY[it].x, PY[it].y, PY[it].z, PY[it].w};
      #pragma unroll
      for (int e = 0; e < 4; ++e) {
        xv[e] = fmaf(xv[e], 0.5f, 0.5f);
        yv[e] = fmaf(yv[e], 0.5f, 0.5f);
        sad[it][e] += fabsf(xv[e] - yv[e]);
      }
      const int off = r * SSTR + sc;
      *(uint2*)(XQ + 0 * PLN + off) = make_uint2(f2bf_pk(xv[0], xv[1]), f2bf_pk(xv[2], xv[3]));
      *(uint2*)(XQ + 1 * PLN + off) = make_uint2(f2bf_pk(yv[0], yv[1]), f2bf_pk(yv[2], yv[3]));
    }
  };

  f32x4 V[5];
  WFrag W;
  bf16x8 AF[5][2];   // per-channel A-fragments: x, y, x^2, y^2, xy

  // ---- load x/y A-frags from staged XQ, derive squared planes in regs ----
  // Caller must ensure a barrier ordered the XQ stores before this, and a
  // barrier after it before any conv H-store (which aliases XQ).
  auto load_derive = [&]() {
    const int l16 = lane & 15, quad = lane >> 4;
    const ush* xp = XQ + (wave * 16 + l16) * SSTR + quad * 8;
    AF[0][0] = *(const bf16x8*)xp;
    AF[0][1] = *(const bf16x8*)(xp + 32);
    AF[1][0] = *(const bf16x8*)(xp + PLN);
    AF[1][1] = *(const bf16x8*)(xp + PLN + 32);
    #pragma unroll
    for (int c = 0; c < 2; ++c) {
      float xf[8], yf[8];
      #pragma unroll
      for (int e = 0; e < 8; ++e) {
        union { unsigned u; float f; } ax, ay;
        ax.u = ((unsigned)(ush)AF[0][c][e]) << 16;
        ay.u = ((unsigned)(ush)AF[1][c][e]) << 16;
        xf[e] = ax.f; yf[e] = ay.f;
      }
      union { unsigned u[4]; bf16x8 v; } w2, w3, w4;
      #pragma unroll
      for (int p = 0; p < 4; ++p) {
        w2.u[p] = f2bf_pk(xf[2*p] * xf[2*p], xf[2*p+1] * xf[2*p+1]);
        w3.u[p] = f2bf_pk(yf[2*p] * yf[2*p], yf[2*p+1] * yf[2*p+1]);
        w4.u[p] = f2bf_pk(xf[2*p] * yf[2*p], xf[2*p+1] * yf[2*p+1]);
      }
      AF[2][c] = w2.v; AF[3][c] = w3.v; AF[4][c] = w4.v;
    }
  };

  // ======== ch0: sigma 0.5 (x3), sigma 1 (x2) ========
  stage();
  issue_loads(1);
  __syncthreads();                              // XQ staged
  load_derive();
  build_wm<0>(WM, wf5, tid, wave, lane, W);     // leading bar: derive reads done before PT stores
  conv_pass<5>(AF, W, PTB, wave, lane, V);
  ssim_fold(V, 3, false, PIcs);
  build_wm<1>(WM, wf5, tid, wave, lane, W);     // leading bar: prior V-PT reads done
  conv_pass<5>(AF, W, PTB, wave, lane, V);      // AF reused
  ssim_fold(V, 2, false, PIcs);

  // ======== ch1: sigma 1 (x1, W reused), sigma 2 (x3), sigma 4 (x1) ======
  __syncthreads();                              // ch0 V-PT reads done before restage (alias)
  stage();
  issue_loads(2);
  __syncthreads();                              // XQ staged
  load_derive();
  __syncthreads();                              // derive reads done before PT stores (W reused)
  conv_pass<5>(AF, W, PTB, wave, lane, V);
  ssim_fold(V, 1, false, PIcs);
  build_wm<2>(WM, wf5, tid, wave, lane, W);
  conv_pass<5>(AF, W, PTB, wave, lane, V);      // AF reused
  ssim_fold(V, 3, false, PIcs);
  build_wm<3>(WM, wf5, tid, wave, lane, W);
  conv_pass<5>(AF, W, PTB, wave, lane, V);      // AF reused
  ssim_fold(V, 1, false, PIcs);

  // ======== ch2: sigma 4 (x2, W reused), sigma 8 (x3 + l^3) ========
  __syncthreads();                              // ch1 V-PT reads done before restage
  stage();
  __syncthreads();                              // XQ staged
  load_derive();
  __syncthreads();                              // derive reads done before PT stores
  conv_pass<5>(AF, W, PTB, wave, lane, V);
  ssim_fold(V, 2, false, PIcs);
  build_wm<4>(WM, wf5, tid, wave, lane, W);
  conv_pass<5>(AF, W, PTB, wave, lane, V);      // AF reused
  ssim_fold(V, 3, true, PIcs);

  // ======== deferred gaussian L1: conv(SAD, sigma 8) (W frags reused) ========
  __syncthreads();                              // ch2 V-PT reads done before SAD writes (alias)
  #pragma unroll
  for (int it = 0; it < 4; ++it) {
    const int off = (it * 16 + sr) * SSTR + sc;
    *(uint2*)(SADP + off) =
        make_uint2(f2bf_pk(sad[it][0], sad[it][1]), f2bf_pk(sad[it][2], sad[it][3]));
  }
  __syncthreads();                              // SAD plane staged
  bf16x8 SF[1][2];
  {
    const ush* sp = SADP + (wave * 16 + (lane & 15)) * SSTR + (lane >> 4) * 8;
    SF[0][0] = *(const bf16x8*)sp;
    SF[0][1] = *(const bf16x8*)(sp + 32);
  }
  // conv_pass<1> H-stores touch only PT plane 0 (region bytes < PTPLN),
  // disjoint from SADP -- no race with other waves' SF reads.
  f32x4 V1[1];
  conv_pass<1>(SF, W, PTB, wave, lane, V1);

  // absacc = central sum of SAD regs (rows 16..47 are it=1,2; cols via sc)
  float absacc = 0.f;
  if (sc >= 16 && sc < 48) {
    #pragma unroll
    for (int it = 1; it <= 2; ++it)
      #pragma unroll
      for (int e = 0; e < 4; ++e) absacc += sad[it][e];
  }

  float mixsum = 0.f;
  #pragma unroll
  for (int r = 0; r < 4; ++r) {
    const float ssim = 1.f - PIcs[r];
    mixsum += 200.f * (0.025f * ssim + 0.975f * (V1[0][r] * (1.f / 3.f)));
  }

  #pragma unroll
  for (int off = 32; off > 0; off >>= 1) {
    mixsum += __shfl_down(mixsum, off);
    absacc += __shfl_down(absacc, off);
    d2     += __shfl_down(d2, off);
  }
  if (lane == 0) { red[wave] = mixsum; red[4 + wave] = absacc; red[8 + wave] = d2; }
  __syncthreads();
  if (tid == 0) {
    float m = 0.f, a = 0.f, d = 0.f;
    #pragma unroll
    for (int i = 0; i < 4; ++i) { m += red[i]; a += red[4 + i]; d += red[8 + i]; }
    partials[3 * blk + 0] = m;
    partials[3 * blk + 1] = a;
    partials[3 * blk + 2] = d;
  }
}

__global__ __launch_bounds__(512)
void msssim_final_kernel(const float* __restrict__ partials,
                         float* __restrict__ out) {
  __shared__ float red[24];
  const int tid = threadIdx.x;
  float m = 0.f, a = 0.f, d2 = 0.f;
  for (int j = tid; j < 2048; j += 512) {
    m  += partials[3 * j + 0];
    a  += partials[3 * j + 1];
    d2 += partials[3 * j + 2];
  }
  #pragma unroll
  for (int off = 32; off > 0; off >>= 1) {
    m  += __shfl_down(m, off);
    a  += __shfl_down(a, off);
    d2 += __shfl_down(d2, off);
  }
  const int wave = tid >> 6, lane = tid & 63;
  if (lane == 0) { red[wave] = m; red[8 + wave] = a; red[16 + wave] = d2; }
  __syncthreads();
  if (tid == 0) {
    float sm = 0.f, sa = 0.f, sd = 0.f;
    #pragma unroll
    for (int i = 0; i < 8; ++i) { sm += red[i]; sa += red[8 + i]; sd += red[16 + i]; }
    const float mix_mean  = sm / (8.f * 512.f * 512.f);
    const float abs_mean  = sa / (8.f * 3.f * 512.f * 512.f);
    const float disc_mean = sd / (8.f * 62.f * 62.f);
    out[0] = 0.5f * (mix_mean + 100.f * abs_mean + disc_mean);
  }
}

extern "C" void kernel_launch(void* const* d_in, const int* in_sizes, int n_in,
                              void* d_out, int out_size, void* d_ws, size_t ws_size,
                              hipStream_t stream) {
  const float* x    = (const float*)d_in[0];
  const float* y    = (const float*)d_in[1];
  const float* disc = (const float*)d_in[2];
  // d_in[3] = g_masks (unused: weights recomputed on device)
  float* partials = (float*)d_ws;   // 2048*3 floats, fully overwritten each call
  dim3 grid(16, 16, 8);
  msssim_fused_kernel<<<grid, NT, 0, stream>>>(x, y, disc, partials);
  msssim_final_kernel<<<1, 512, 0, stream>>>(partials, (float*)d_out);
}

// Round 5
// 144.179 us; speedup vs baseline: 1.0032x; 1.0032x over previous
//
#include <hip/hip_runtime.h>
#include <stdint.h>

// MS-SSIM + L1 fused loss, MI355X.
// R16 = R15 resubmit with the unverified inline-asm cvt_pk reverted to the
// verified perm-based pack (bit-identical numerics to R10-R14).
// R15 theory under test: R14 falsified occupancy (time invariant to LDS
// 74.7->28.7KB) -> per-CU work bound: VALU ~50%, LDS pipe ~55% by instruction
// count. Remove the XQ staging round-trip entirely: the MFMA A-fragment is
// pixel(row=wave*16+l16, col=32c+quad*8+e), loadable DIRECTLY from global as
// two float4 pairs per chunk (same bytes, HBM at 12%). Deletes per thread:
// 24 b64 LDS writes + 12 b128 reads (stage/derive), SAD restage (4 w + 2 r),
// ~600 VALU staging ops, and the XQ region + its alias barriers. SAD stays in
// registers (already fragment-layout) and feeds the sigma-8 conv directly.
// OOB semantics preserved: raw=0 -> 0.5 after denorm (same as staged path).
// Weights/conv/epilogue identical to R14 (numerically verified).

#define TILE 32
#define HALO 16
#define SSTR 72            // bf16 stride (144B row, 16B-multiple)
#define PTPLN (32 * SSTR)
#define NT   256

#define C1c 1.0e-4f
#define C2c 9.0e-4f

typedef short bf16x8 __attribute__((ext_vector_type(8)));
typedef float f32x4  __attribute__((ext_vector_type(4)));
typedef unsigned short ush;

// ---- compile-time 1/sum of the 33-tap gaussian ----
constexpr double cexp(double xx) {
  if (xx < -700.0) return 0.0;
  const double ln2 = 0.6931471805599453, il2 = 1.4426950408889634;
  double kd = xx * il2;
  long long k = (long long)(kd + (kd >= 0 ? 0.5 : -0.5));
  double r = xx - (double)k * ln2;
  double t = 1.0, s = 1.0;
  for (int i = 1; i <= 22; ++i) { t *= r / (double)i; s += t; }
  double p = 1.0, base = (k >= 0) ? 2.0 : 0.5;
  long long n = (k >= 0) ? k : -k;
  while (n) { if (n & 1) p *= base; base *= base; n >>= 1; }
  return s * p;
}
constexpr float gsi(double sigma) {
  double inv = 1.0 / (2.0 * sigma * sigma);
  double s = 0.0;
  for (int k = -16; k <= 16; ++k) s += cexp(-(double)(k * k) * inv);
  return (float)(1.0 / s);
}
constexpr float SI05 = gsi(0.5), SI10 = gsi(1.0), SI20 = gsi(2.0),
                SI40 = gsi(4.0), SI80 = gsi(8.0);

// pack two f32 -> bf16x2 (round-half-up; verified bit-exact vs R10-R14)
__device__ __forceinline__ unsigned f2bf_pk(float lo, float hi) {
  union { float f; unsigned u; } a, b; a.f = lo; b.f = hi;
  return __builtin_amdgcn_perm(b.u + 0x8000u, a.u + 0x8000u, 0x07060302u);
}
__device__ __forceinline__ ush f2bf1(float f) {
  union { float f; unsigned u; } c; c.f = f;
  return (ush)((c.u + 0x8000u) >> 16);
}

struct WFrag {
  bf16x8 h[2][2];   // [nt][kchunk] : H-pass B-operand; V-pass A-operand is h[wave>>1]
};

// Fill WM[m][k] = wf5[SIG][k-m] (k-m in [0,32] else 0), then load H frags.
template<int SIG>
__device__ __forceinline__ void build_wm(ush* __restrict__ WM,
                                         const float (*__restrict__ wf5)[40],
                                         int tid, int wave, int lane,
                                         WFrag& W) {
  __syncthreads();                 // prior PT/WM readers ordered (doubles as inter-pass bar)
  #pragma unroll
  for (int i = 0; i < 8; ++i) {
    const int idx = i * 256 + tid;         // 0..2047
    const int m = idx >> 6, k = idx & 63;
    const int t = k - m;
    const int tc = t < 0 ? 0 : (t > 32 ? 32 : t);
    float v = wf5[SIG][tc];
    v = (t >= 0 && t <= 32) ? v : 0.f;
    WM[m * SSTR + k] = f2bf1(v);
  }
  __syncthreads();                 // WM ready
  const int l16 = lane & 15, quad = lane >> 4;
  #pragma unroll
  for (int t = 0; t < 2; ++t)
    #pragma unroll
    for (int c = 0; c < 2; ++c)
      W.h[t][c] = *(const bf16x8*)(WM + (t * 16 + l16) * SSTR + quad * 8 + 32 * c);
}

// One separable conv pass via two banded GEMMs; A-fragments and all weights
// from registers (V weights = W.h[wave>>1], wave-uniform select).
// Caller must ensure a barrier ordered prior PT readers before entry.
template<int NQ>
__device__ __forceinline__ void conv_pass(const bf16x8 (&A)[NQ][2],
                                          const WFrag& W,
                                          ush* __restrict__ PT,
                                          int wave, int lane, f32x4* V) {
  const int l16 = lane & 15, quad = lane >> 4;
  const int m0 = wave * 16;
  // H-GEMM: D(64x32) = A(64x64) x Wh; store transposed bf16 into PT
  #pragma unroll
  for (int q = 0; q < NQ; ++q) {
    #pragma unroll
    for (int nt = 0; nt < 2; ++nt) {
      f32x4 acc = {0.f, 0.f, 0.f, 0.f};
      acc = __builtin_amdgcn_mfma_f32_16x16x32_bf16(A[q][0], W.h[nt][0], acc, 0, 0, 0);
      acc = __builtin_amdgcn_mfma_f32_16x16x32_bf16(A[q][1], W.h[nt][1], acc, 0, 0, 0);
      uint2 u;
      u.x = f2bf_pk(acc[0], acc[1]);
      u.y = f2bf_pk(acc[2], acc[3]);
      *(uint2*)(PT + q * PTPLN + (nt * 16 + l16) * SSTR + m0 + quad * 4) = u;
    }
  }
  // V-pass A-operand: identical lane addressing to W.h[wave>>1] (wave-uniform)
  const bf16x8 wv0 = (wave & 2) ? W.h[1][0] : W.h[0][0];
  const bf16x8 wv1 = (wave & 2) ? W.h[1][1] : W.h[0][1];
  __syncthreads();                 // PT complete
  // V-GEMM: D(32x32) = Wv(32x64) x P
  const int n0 = (wave & 1) * 16;
  #pragma unroll
  for (int q = 0; q < NQ; ++q) {
    const ush* pp = PT + q * PTPLN + (n0 + l16) * SSTR + quad * 8;
    const bf16x8 b0 = *(const bf16x8*)pp;
    const bf16x8 b1 = *(const bf16x8*)(pp + 32);
    f32x4 acc = {0.f, 0.f, 0.f, 0.f};
    acc = __builtin_amdgcn_mfma_f32_16x16x32_bf16(wv0, b0, acc, 0, 0, 0);
    acc = __builtin_amdgcn_mfma_f32_16x16x32_bf16(wv1, b1, acc, 0, 0, 0);
    V[q] = acc;
  }
}

// SSIM epilogue on V[5]
__device__ __forceinline__ void ssim_fold(const f32x4* V, int mult, bool last,
                                          float* PIcs) {
  #pragma unroll
  for (int r = 0; r < 4; ++r) {
    const float mux = V[0][r], muy = V[1][r];
    const float A = mux * muy;
    const float Bq = mux * mux + muy * muy;
    const float S = V[2][r] + V[3][r] - Bq;
    const float sxy = V[4][r] - A;
    const float cs = (2.f * sxy + C2c) * __builtin_amdgcn_rcpf(S + C2c);
    float p = cs;
    if (mult >= 2) p *= cs;
    if (mult >= 3) p *= cs;
    if (last) {
      const float l = (2.f * A + C1c) * __builtin_amdgcn_rcpf(Bq + C1c);
      p *= l * l * l;
    }
    PIcs[r] *= p;
  }
}

__global__ __launch_bounds__(NT)
void msssim_fused_kernel(const float* __restrict__ x, const float* __restrict__ y,
                         const float* __restrict__ disc,
                         float* __restrict__ partials) {
  __shared__ ush PT[5 * PTPLN];         // 23040 B (H->V transpose only)
  __shared__ ush WM[32 * SSTR];
  __shared__ float wf5[5][40];
  __shared__ float red[12];

  const int tid = threadIdx.x;
  const int wave = tid >> 6, lane = tid & 63;
  const int l16 = lane & 15, quad = lane >> 4;
  const int bx = blockIdx.x, by = blockIdx.y, b = blockIdx.z;
  const int x0 = bx * TILE - HALO, y0 = by * TILE - HALO;
  const int blk = (b * 16 + by) * 16 + bx;

  // per-lane fragment coordinates (row fixed per lane; two 8-col chunks)
  const int gy = y0 + wave * 16 + l16;
  const int cbase = x0 + quad * 8;
  const bool rowok = (gy >= 0) && (gy < 512);

  // disc^2 partial (16 elems/block), issued early so latency hides
  float d2 = 0.f;
  { const int di = blk * 16 + tid;
    if (tid < 16 && di < 8 * 62 * 62) { const float dd = disc[di] - 1.f; d2 = dd * dd; } }

  // one-time tap tables (first build_wm's leading barrier orders readers)
  if (tid < 165) {
    const int sig = tid / 33;
    const int k = tid - sig * 33;
    const float d = (float)(k - 16);
    float inv, si;
    if (sig == 0)      { inv = 2.0f;       si = SI05; }
    else if (sig == 1) { inv = 0.5f;       si = SI10; }
    else if (sig == 2) { inv = 0.125f;     si = SI20; }
    else if (sig == 3) { inv = 0.03125f;   si = SI40; }
    else               { inv = 0.0078125f; si = SI80; }
    wf5[sig][k] = __expf(-d * d * inv) * si;
  }

  float xr[16], yr[16];   // raw per-lane fragment loads, [chunk*8 + e]
  auto frag_loads = [&](int ch) {
    const float* __restrict__ xs = x + (size_t)(b * 3 + ch) * 262144;
    const float* __restrict__ ys = y + (size_t)(b * 3 + ch) * 262144;
    #pragma unroll
    for (int c = 0; c < 2; ++c) {
      const int g0 = cbase + 32 * c;
      if (rowok && g0 >= 0 && g0 <= 504) {
        const float* px = xs + gy * 512 + g0;
        const float* py = ys + gy * 512 + g0;
        const float4 a0 = *(const float4*)px;
        const float4 a1 = *(const float4*)(px + 4);
        const float4 b0 = *(const float4*)py;
        const float4 b1 = *(const float4*)(py + 4);
        xr[c*8+0]=a0.x; xr[c*8+1]=a0.y; xr[c*8+2]=a0.z; xr[c*8+3]=a0.w;
        xr[c*8+4]=a1.x; xr[c*8+5]=a1.y; xr[c*8+6]=a1.z; xr[c*8+7]=a1.w;
        yr[c*8+0]=b0.x; yr[c*8+1]=b0.y; yr[c*8+2]=b0.z; yr[c*8+3]=b0.w;
        yr[c*8+4]=b1.x; yr[c*8+5]=b1.y; yr[c*8+6]=b1.z; yr[c*8+7]=b1.w;
      } else {
        #pragma unroll
        for (int e = 0; e < 8; ++e) {
          const int g = g0 + e;
          const bool ok = rowok && (g >= 0) && (g < 512);
          xr[c*8+e] = ok ? xs[gy * 512 + g] : 0.f;
          yr[c*8+e] = ok ? ys[gy * 512 + g] : 0.f;
        }
      }
    }
  };

  float PIcs[4] = {1.f, 1.f, 1.f, 1.f};
  float sadf[16];          // sum over channels of |x-y|, fragment layout
  #pragma unroll
  for (int e = 0; e < 16; ++e) sadf[e] = 0.f;

  f32x4 V[5];
  WFrag W;
  bf16x8 AF[5][2];   // per-channel A-fragments: x, y, x^2, y^2, xy

  // denormalize + derive all 5 plane fragments in registers; accumulate SAD
  auto derive = [&]() {
    #pragma unroll
    for (int c = 0; c < 2; ++c) {
      float xf[8], yf[8];
      #pragma unroll
      for (int e = 0; e < 8; ++e) {
        xf[e] = fmaf(xr[c*8+e], 0.5f, 0.5f);
        yf[e] = fmaf(yr[c*8+e], 0.5f, 0.5f);
        sadf[c*8+e] += fabsf(xf[e] - yf[e]);
      }
      union { unsigned u[4]; bf16x8 v; } w0, w1, w2, w3, w4;
      #pragma unroll
      for (int p = 0; p < 4; ++p) {
        w0.u[p] = f2bf_pk(xf[2*p],           xf[2*p+1]);
        w1.u[p] = f2bf_pk(yf[2*p],           yf[2*p+1]);
        w2.u[p] = f2bf_pk(xf[2*p]*xf[2*p],   xf[2*p+1]*xf[2*p+1]);
        w3.u[p] = f2bf_pk(yf[2*p]*yf[2*p],   yf[2*p+1]*yf[2*p+1]);
        w4.u[p] = f2bf_pk(xf[2*p]*yf[2*p],   xf[2*p+1]*yf[2*p+1]);
      }
      AF[0][c] = w0.v; AF[1][c] = w1.v; AF[2][c] = w2.v;
      AF[3][c] = w3.v; AF[4][c] = w4.v;
    }
  };

  // ======== ch0: sigma 0.5 (x3), sigma 1 (x2) ========
  frag_loads(0);
  derive();
  frag_loads(1);                                // in flight during ch0 convs
  build_wm<0>(WM, wf5, tid, wave, lane, W);     // leading bar also orders wf5
  conv_pass<5>(AF, W, PT, wave, lane, V);
  ssim_fold(V, 3, false, PIcs);
  build_wm<1>(WM, wf5, tid, wave, lane, W);
  conv_pass<5>(AF, W, PT, wave, lane, V);
  ssim_fold(V, 2, false, PIcs);

  // ======== ch1: sigma 1 (x1, W reused), sigma 2 (x3), sigma 4 (x1) ======
  derive();
  frag_loads(2);                                // in flight during ch1 convs
  __syncthreads();                              // prior V-PT reads done
  conv_pass<5>(AF, W, PT, wave, lane, V);
  ssim_fold(V, 1, false, PIcs);
  build_wm<2>(WM, wf5, tid, wave, lane, W);
  conv_pass<5>(AF, W, PT, wave, lane, V);
  ssim_fold(V, 3, false, PIcs);
  build_wm<3>(WM, wf5, tid, wave, lane, W);
  conv_pass<5>(AF, W, PT, wave, lane, V);
  ssim_fold(V, 1, false, PIcs);

  // ======== ch2: sigma 4 (x2, W reused), sigma 8 (x3 + l^3) ========
  derive();
  __syncthreads();                              // prior V-PT reads done
  conv_pass<5>(AF, W, PT, wave, lane, V);
  ssim_fold(V, 2, false, PIcs);
  build_wm<4>(WM, wf5, tid, wave, lane, W);
  conv_pass<5>(AF, W, PT, wave, lane, V);
  ssim_fold(V, 3, true, PIcs);

  // ======== gaussian L1: conv(SAD, sigma 8); SAD already in frag layout ====
  bf16x8 SF[1][2];
  #pragma unroll
  for (int c = 0; c < 2; ++c) {
    union { unsigned u[4]; bf16x8 v; } w;
    #pragma unroll
    for (int p = 0; p < 4; ++p)
      w.u[p] = f2bf_pk(sadf[c*8+2*p], sadf[c*8+2*p+1]);
    SF[0][c] = w.v;
  }
  __syncthreads();                              // prior V-PT reads done
  f32x4 V1[1];
  conv_pass<1>(SF, W, PT, wave, lane, V1);

  // absacc = central sum of SAD regs: rows 16..47 -> waves 1,2;
  // cols 16..31 -> chunk0/quads 2,3; cols 32..47 -> chunk1/quads 0,1.
  float absacc = 0.f;
  if (wave == 1 || wave == 2) {
    if (quad >= 2) {
      #pragma unroll
      for (int e = 0; e < 8; ++e) absacc += sadf[e];
    } else {
      #pragma unroll
      for (int e = 0; e < 8; ++e) absacc += sadf[8 + e];
    }
  }

  float mixsum = 0.f;
  #pragma unroll
  for (int r = 0; r < 4; ++r) {
    const float ssim = 1.f - PIcs[r];
    mixsum += 200.f * (0.025f * ssim + 0.975f * (V1[0][r] * (1.f / 3.f)));
  }

  #pragma unroll
  for (int off = 32; off > 0; off >>= 1) {
    mixsum += __shfl_down(mixsum, off);
    absacc += __shfl_down(absacc, off);
    d2     += __shfl_down(d2, off);
  }
  if (lane == 0) { red[wave] = mixsum; red[4 + wave] = absacc; red[8 + wave] = d2; }
  __syncthreads();
  if (tid == 0) {
    float m = 0.f, a = 0.f, d = 0.f;
    #pragma unroll
    for (int i = 0; i < 4; ++i) { m += red[i]; a += red[4 + i]; d += red[8 + i]; }
    partials[3 * blk + 0] = m;
    partials[3 * blk + 1] = a;
    partials[3 * blk + 2] = d;
  }
}

__global__ __launch_bounds__(512)
void msssim_final_kernel(const float* __restrict__ partials,
                         float* __restrict__ out) {
  __shared__ float red[24];
  const int tid = threadIdx.x;
  float m = 0.f, a = 0.f, d2 = 0.f;
  for (int j = tid; j < 2048; j += 512) {
    m  += partials[3 * j + 0];
    a  += partials[3 * j + 1];
    d2 += partials[3 * j + 2];
  }
  #pragma unroll
  for (int off = 32; off > 0; off >>= 1) {
    m  += __shfl_down(m, off);
    a  += __shfl_down(a, off);
    d2 += __shfl_down(d2, off);
  }
  const int wave = tid >> 6, lane = tid & 63;
  if (lane == 0) { red[wave] = m; red[8 + wave] = a; red[16 + wave] = d2; }
  __syncthreads();
  if (tid == 0) {
    float sm = 0.f, sa = 0.f, sd = 0.f;
    #pragma unroll
    for (int i = 0; i < 8; ++i) { sm += red[i]; sa += red[8 + i]; sd += red[16 + i]; }
    const float mix_mean  = sm / (8.f * 512.f * 512.f);
    const float abs_mean  = sa / (8.f * 3.f * 512.f * 512.f);
    const float disc_mean = sd / (8.f * 62.f * 62.f);
    out[0] = 0.5f * (mix_mean + 100.f * abs_mean + disc_mean);
  }
}

extern "C" void kernel_launch(void* const* d_in, const int* in_sizes, int n_in,
                              void* d_out, int out_size, void* d_ws, size_t ws_size,
                              hipStream_t stream) {
  const float* x    = (const float*)d_in[0];
  const float* y    = (const float*)d_in[1];
  const float* disc = (const float*)d_in[2];
  // d_in[3] = g_masks (unused: weights recomputed on device)
  float* partials = (float*)d_ws;   // 2048*3 floats, fully overwritten each call
  dim3 grid(16, 16, 8);
  msssim_fused_kernel<<<grid, NT, 0, stream>>>(x, y, disc, partials);
  msssim_final_kernel<<<1, 512, 0, stream>>>(partials, (float*)d_out);
}

// Round 6
// 141.777 us; speedup vs baseline: 1.0202x; 1.0169x over previous
//
#include <hip/hip_runtime.h>
#include <stdint.h>

// MS-SSIM + L1 fused loss, MI355X.
// R17: batch sigmas per barrier. R13/R14/R16 proved time (~72us) is invariant
// to occupancy (2->5 blk/CU), LDS traffic (-40%) and VALU count (-15%), with
// no pipe >50% -> the cost is the phase/barrier skeleton itself (26 barriers,
// pipes alternate instead of overlap). This round keeps R16's instruction
// counts but restructures synchronization:
//   - WM5: all 5 weight matrices built ONCE (23KB LDS), not 5 rebuilds
//   - per channel, H-GEMMs for BOTH sigmas (+SAD conv in ch2) run in one
//     phase into 10-11 PT planes (50.7KB), ONE barrier, then all V-GEMMs
//   - barriers 26 -> 10, serialized phases 13 -> 5, 40+ MFMA issue per phase
// LDS rises to ~74.5KB (2 blk/CU) deliberately -- R14 showed residency >2 is
// worthless. Fold order into PIcs unchanged -> bit-identical output.

#define TILE 32
#define HALO 16
#define SSTR 72            // bf16 stride (144B row, 16B-multiple)
#define PTPLN (32 * SSTR)
#define WMSZ  (32 * SSTR)
#define NT   256

#define C1c 1.0e-4f
#define C2c 9.0e-4f

typedef short bf16x8 __attribute__((ext_vector_type(8)));
typedef float f32x4  __attribute__((ext_vector_type(4)));
typedef unsigned short ush;

// ---- compile-time 1/sum of the 33-tap gaussian ----
constexpr double cexp(double xx) {
  if (xx < -700.0) return 0.0;
  const double ln2 = 0.6931471805599453, il2 = 1.4426950408889634;
  double kd = xx * il2;
  long long k = (long long)(kd + (kd >= 0 ? 0.5 : -0.5));
  double r = xx - (double)k * ln2;
  double t = 1.0, s = 1.0;
  for (int i = 1; i <= 22; ++i) { t *= r / (double)i; s += t; }
  double p = 1.0, base = (k >= 0) ? 2.0 : 0.5;
  long long n = (k >= 0) ? k : -k;
  while (n) { if (n & 1) p *= base; base *= base; n >>= 1; }
  return s * p;
}
constexpr float gsi(double sigma) {
  double inv = 1.0 / (2.0 * sigma * sigma);
  double s = 0.0;
  for (int k = -16; k <= 16; ++k) s += cexp(-(double)(k * k) * inv);
  return (float)(1.0 / s);
}
constexpr float SI05 = gsi(0.5), SI10 = gsi(1.0), SI20 = gsi(2.0),
                SI40 = gsi(4.0), SI80 = gsi(8.0);

// pack two f32 -> bf16x2 (round-half-up; verified bit-exact vs R10-R16)
__device__ __forceinline__ unsigned f2bf_pk(float lo, float hi) {
  union { float f; unsigned u; } a, b; a.f = lo; b.f = hi;
  return __builtin_amdgcn_perm(b.u + 0x8000u, a.u + 0x8000u, 0x07060302u);
}
__device__ __forceinline__ ush f2bf1(float f) {
  union { float f; unsigned u; } c; c.f = f;
  return (ush)((c.u + 0x8000u) >> 16);
}

struct WFrag {
  bf16x8 h[2][2];   // [nt][kchunk] : H-pass B-operand; V-pass A-operand is h[wave>>1]
};

// H-GEMM for NQ planes into PT planes [bp..bp+NQ)
template<int NQ>
__device__ __forceinline__ void conv_h(const bf16x8 (&A)[NQ][2], const WFrag& W,
                                       ush* __restrict__ PT, int bp,
                                       int wave, int lane) {
  const int l16 = lane & 15, quad = lane >> 4;
  const int m0 = wave * 16;
  #pragma unroll
  for (int q = 0; q < NQ; ++q) {
    #pragma unroll
    for (int nt = 0; nt < 2; ++nt) {
      f32x4 acc = {0.f, 0.f, 0.f, 0.f};
      acc = __builtin_amdgcn_mfma_f32_16x16x32_bf16(A[q][0], W.h[nt][0], acc, 0, 0, 0);
      acc = __builtin_amdgcn_mfma_f32_16x16x32_bf16(A[q][1], W.h[nt][1], acc, 0, 0, 0);
      uint2 u;
      u.x = f2bf_pk(acc[0], acc[1]);
      u.y = f2bf_pk(acc[2], acc[3]);
      *(uint2*)(PT + (bp + q) * PTPLN + (nt * 16 + l16) * SSTR + m0 + quad * 4) = u;
    }
  }
}

// V-GEMM reading PT planes [bp..bp+NQ); weights from W (wave-uniform select)
template<int NQ>
__device__ __forceinline__ void conv_v(const WFrag& W, const ush* __restrict__ PT,
                                       int bp, int wave, int lane, f32x4* V) {
  const int l16 = lane & 15, quad = lane >> 4;
  const bf16x8 wv0 = (wave & 2) ? W.h[1][0] : W.h[0][0];
  const bf16x8 wv1 = (wave & 2) ? W.h[1][1] : W.h[0][1];
  const int n0 = (wave & 1) * 16;
  #pragma unroll
  for (int q = 0; q < NQ; ++q) {
    const ush* pp = PT + (bp + q) * PTPLN + (n0 + l16) * SSTR + quad * 8;
    const bf16x8 b0 = *(const bf16x8*)pp;
    const bf16x8 b1 = *(const bf16x8*)(pp + 32);
    f32x4 acc = {0.f, 0.f, 0.f, 0.f};
    acc = __builtin_amdgcn_mfma_f32_16x16x32_bf16(wv0, b0, acc, 0, 0, 0);
    acc = __builtin_amdgcn_mfma_f32_16x16x32_bf16(wv1, b1, acc, 0, 0, 0);
    V[q] = acc;
  }
}

// SSIM epilogue on V[5]
__device__ __forceinline__ void ssim_fold(const f32x4* V, int mult, bool last,
                                          float* PIcs) {
  #pragma unroll
  for (int r = 0; r < 4; ++r) {
    const float mux = V[0][r], muy = V[1][r];
    const float A = mux * muy;
    const float Bq = mux * mux + muy * muy;
    const float S = V[2][r] + V[3][r] - Bq;
    const float sxy = V[4][r] - A;
    const float cs = (2.f * sxy + C2c) * __builtin_amdgcn_rcpf(S + C2c);
    float p = cs;
    if (mult >= 2) p *= cs;
    if (mult >= 3) p *= cs;
    if (last) {
      const float l = (2.f * A + C1c) * __builtin_amdgcn_rcpf(Bq + C1c);
      p *= l * l * l;
    }
    PIcs[r] *= p;
  }
}

__global__ __launch_bounds__(NT)
void msssim_fused_kernel(const float* __restrict__ x, const float* __restrict__ y,
                         const float* __restrict__ disc,
                         float* __restrict__ partials) {
  __shared__ ush PT[11 * PTPLN];        // 50688 B: two 5-plane sigma sets + SAD
  __shared__ ush WM5[5 * WMSZ];         // 23040 B: all 5 weight matrices
  __shared__ float wf5[5][40];
  __shared__ float red[12];

  const int tid = threadIdx.x;
  const int wave = tid >> 6, lane = tid & 63;
  const int l16 = lane & 15, quad = lane >> 4;
  const int bx = blockIdx.x, by = blockIdx.y, b = blockIdx.z;
  const int x0 = bx * TILE - HALO, y0 = by * TILE - HALO;
  const int blk = (b * 16 + by) * 16 + bx;

  // per-lane fragment coordinates (row fixed per lane; two 8-col chunks)
  const int gy = y0 + wave * 16 + l16;
  const int cbase = x0 + quad * 8;
  const bool rowok = (gy >= 0) && (gy < 512);

  // disc^2 partial (16 elems/block), issued early so latency hides
  float d2 = 0.f;
  { const int di = blk * 16 + tid;
    if (tid < 16 && di < 8 * 62 * 62) { const float dd = disc[di] - 1.f; d2 = dd * dd; } }

  // one-time tap tables
  if (tid < 165) {
    const int sig = tid / 33;
    const int k = tid - sig * 33;
    const float d = (float)(k - 16);
    float inv, si;
    if (sig == 0)      { inv = 2.0f;       si = SI05; }
    else if (sig == 1) { inv = 0.5f;       si = SI10; }
    else if (sig == 2) { inv = 0.125f;     si = SI20; }
    else if (sig == 3) { inv = 0.03125f;   si = SI40; }
    else               { inv = 0.0078125f; si = SI80; }
    wf5[sig][k] = __expf(-d * d * inv) * si;
  }

  float xr[16], yr[16];   // raw per-lane fragment loads, [chunk*8 + e]
  auto frag_loads = [&](int ch) {
    const float* __restrict__ xs = x + (size_t)(b * 3 + ch) * 262144;
    const float* __restrict__ ys = y + (size_t)(b * 3 + ch) * 262144;
    #pragma unroll
    for (int c = 0; c < 2; ++c) {
      const int g0 = cbase + 32 * c;
      if (rowok && g0 >= 0 && g0 <= 504) {
        const float* px = xs + gy * 512 + g0;
        const float* py = ys + gy * 512 + g0;
        const float4 a0 = *(const float4*)px;
        const float4 a1 = *(const float4*)(px + 4);
        const float4 b0 = *(const float4*)py;
        const float4 b1 = *(const float4*)(py + 4);
        xr[c*8+0]=a0.x; xr[c*8+1]=a0.y; xr[c*8+2]=a0.z; xr[c*8+3]=a0.w;
        xr[c*8+4]=a1.x; xr[c*8+5]=a1.y; xr[c*8+6]=a1.z; xr[c*8+7]=a1.w;
        yr[c*8+0]=b0.x; yr[c*8+1]=b0.y; yr[c*8+2]=b0.z; yr[c*8+3]=b0.w;
        yr[c*8+4]=b1.x; yr[c*8+5]=b1.y; yr[c*8+6]=b1.z; yr[c*8+7]=b1.w;
      } else {
        #pragma unroll
        for (int e = 0; e < 8; ++e) {
          const int g = g0 + e;
          const bool ok = rowok && (g >= 0) && (g < 512);
          xr[c*8+e] = ok ? xs[gy * 512 + g] : 0.f;
          yr[c*8+e] = ok ? ys[gy * 512 + g] : 0.f;
        }
      }
    }
  };

  float PIcs[4] = {1.f, 1.f, 1.f, 1.f};
  float sadf[16];          // sum over channels of |x-y|, fragment layout
  #pragma unroll
  for (int e = 0; e < 16; ++e) sadf[e] = 0.f;

  f32x4 V[5];
  bf16x8 AF[5][2];   // per-channel A-fragments: x, y, x^2, y^2, xy

  // denormalize + derive all 5 plane fragments in registers; accumulate SAD
  auto derive = [&]() {
    #pragma unroll
    for (int c = 0; c < 2; ++c) {
      float xf[8], yf[8];
      #pragma unroll
      for (int e = 0; e < 8; ++e) {
        xf[e] = fmaf(xr[c*8+e], 0.5f, 0.5f);
        yf[e] = fmaf(yr[c*8+e], 0.5f, 0.5f);
        sadf[c*8+e] += fabsf(xf[e] - yf[e]);
      }
      union { unsigned u[4]; bf16x8 v; } w0, w1, w2, w3, w4;
      #pragma unroll
      for (int p = 0; p < 4; ++p) {
        w0.u[p] = f2bf_pk(xf[2*p],           xf[2*p+1]);
        w1.u[p] = f2bf_pk(yf[2*p],           yf[2*p+1]);
        w2.u[p] = f2bf_pk(xf[2*p]*xf[2*p],   xf[2*p+1]*xf[2*p+1]);
        w3.u[p] = f2bf_pk(yf[2*p]*yf[2*p],   yf[2*p+1]*yf[2*p+1]);
        w4.u[p] = f2bf_pk(xf[2*p]*yf[2*p],   xf[2*p+1]*yf[2*p+1]);
      }
      AF[0][c] = w0.v; AF[1][c] = w1.v; AF[2][c] = w2.v;
      AF[3][c] = w3.v; AF[4][c] = w4.v;
    }
  };

  auto load_wfrag = [&](int sig, WFrag& W) {
    const ush* base = WM5 + sig * WMSZ;
    #pragma unroll
    for (int t = 0; t < 2; ++t)
      #pragma unroll
      for (int c = 0; c < 2; ++c)
        W.h[t][c] = *(const bf16x8*)(base + (t * 16 + l16) * SSTR + quad * 8 + 32 * c);
  };

  // ---- prologue: loads + WM5 build (2 barriers total) ----
  frag_loads(0);
  derive();
  frag_loads(1);
  __syncthreads();                 // wf5 ready
  #pragma unroll
  for (int i = 0; i < 40; ++i) {
    const int idx = i * 256 + tid;         // 0..10239
    const int sig = idx >> 11;
    const int rem = idx & 2047;
    const int m = rem >> 6, k = rem & 63;
    const int t = k - m;
    const int tc = t < 0 ? 0 : (t > 32 ? 32 : t);
    float v = wf5[sig][tc];
    v = (t >= 0 && t <= 32) ? v : 0.f;
    WM5[sig * WMSZ + m * SSTR + k] = f2bf1(v);
  }
  __syncthreads();                 // WM5 ready (read-only hereafter)

  WFrag WA, WB;
  load_wfrag(0, WA);               // sigma 0.5
  load_wfrag(1, WB);               // sigma 1

  // ======== phase ch0: sigma 0.5 (x3) + sigma 1 (x2) ========
  conv_h<5>(AF, WA, PT, 0, wave, lane);
  conv_h<5>(AF, WB, PT, 5, wave, lane);
  __syncthreads();                 // PT complete
  conv_v<5>(WA, PT, 0, wave, lane, V); ssim_fold(V, 3, false, PIcs);
  conv_v<5>(WB, PT, 5, wave, lane, V); ssim_fold(V, 2, false, PIcs);
  derive();                        // ch1 A-frags
  frag_loads(2);
  load_wfrag(2, WA);               // sigma 2 (sigma 1 stays in WB)
  __syncthreads();                 // V reads done before next H stores

  // ======== phase ch1a: sigma 1 (x1) + sigma 2 (x3) ========
  conv_h<5>(AF, WB, PT, 0, wave, lane);
  conv_h<5>(AF, WA, PT, 5, wave, lane);
  __syncthreads();
  conv_v<5>(WB, PT, 0, wave, lane, V); ssim_fold(V, 1, false, PIcs);
  conv_v<5>(WA, PT, 5, wave, lane, V); ssim_fold(V, 3, false, PIcs);
  load_wfrag(3, WB);               // sigma 4
  __syncthreads();

  // ======== phase ch1b: sigma 4 (x1) ========
  conv_h<5>(AF, WB, PT, 0, wave, lane);
  __syncthreads();
  conv_v<5>(WB, PT, 0, wave, lane, V); ssim_fold(V, 1, false, PIcs);
  derive();                        // ch2 A-frags (sadf now complete)
  load_wfrag(4, WA);               // sigma 8
  bf16x8 SF[1][2];
  #pragma unroll
  for (int c = 0; c < 2; ++c) {
    union { unsigned u[4]; bf16x8 v; } w;
    #pragma unroll
    for (int p = 0; p < 4; ++p)
      w.u[p] = f2bf_pk(sadf[c*8+2*p], sadf[c*8+2*p+1]);
    SF[0][c] = w.v;
  }
  __syncthreads();

  // ======== phase ch2: sigma 4 (x2) + sigma 8 (x3 + l^3) + SAD sigma 8 ====
  conv_h<5>(AF, WB, PT, 0, wave, lane);
  conv_h<5>(AF, WA, PT, 5, wave, lane);
  conv_h<1>(SF, WA, PT, 10, wave, lane);
  __syncthreads();
  conv_v<5>(WB, PT, 0, wave, lane, V); ssim_fold(V, 2, false, PIcs);
  conv_v<5>(WA, PT, 5, wave, lane, V); ssim_fold(V, 3, true, PIcs);
  f32x4 V1[1];
  conv_v<1>(WA, PT, 10, wave, lane, V1);

  // absacc = central sum of SAD regs: rows 16..47 -> waves 1,2;
  // cols 16..31 -> chunk0/quads 2,3; cols 32..47 -> chunk1/quads 0,1.
  float absacc = 0.f;
  if (wave == 1 || wave == 2) {
    if (quad >= 2) {
      #pragma unroll
      for (int e = 0; e < 8; ++e) absacc += sadf[e];
    } else {
      #pragma unroll
      for (int e = 0; e < 8; ++e) absacc += sadf[8 + e];
    }
  }

  float mixsum = 0.f;
  #pragma unroll
  for (int r = 0; r < 4; ++r) {
    const float ssim = 1.f - PIcs[r];
    mixsum += 200.f * (0.025f * ssim + 0.975f * (V1[0][r] * (1.f / 3.f)));
  }

  #pragma unroll
  for (int off = 32; off > 0; off >>= 1) {
    mixsum += __shfl_down(mixsum, off);
    absacc += __shfl_down(absacc, off);
    d2     += __shfl_down(d2, off);
  }
  if (lane == 0) { red[wave] = mixsum; red[4 + wave] = absacc; red[8 + wave] = d2; }
  __syncthreads();
  if (tid == 0) {
    float m = 0.f, a = 0.f, d = 0.f;
    #pragma unroll
    for (int i = 0; i < 4; ++i) { m += red[i]; a += red[4 + i]; d += red[8 + i]; }
    partials[3 * blk + 0] = m;
    partials[3 * blk + 1] = a;
    partials[3 * blk + 2] = d;
  }
}

__global__ __launch_bounds__(512)
void msssim_final_kernel(const float* __restrict__ partials,
                         float* __restrict__ out) {
  __shared__ float red[24];
  const int tid = threadIdx.x;
  float m = 0.f, a = 0.f, d2 = 0.f;
  for (int j = tid; j < 2048; j += 512) {
    m  += partials[3 * j + 0];
    a  += partials[3 * j + 1];
    d2 += partials[3 * j + 2];
  }
  #pragma unroll
  for (int off = 32; off > 0; off >>= 1) {
    m  += __shfl_down(m, off);
    a  += __shfl_down(a, off);
    d2 += __shfl_down(d2, off);
  }
  const int wave = tid >> 6, lane = tid & 63;
  if (lane == 0) { red[wave] = m; red[8 + wave] = a; red[16 + wave] = d2; }
  __syncthreads();
  if (tid == 0) {
    float sm = 0.f, sa = 0.f, sd = 0.f;
    #pragma unroll
    for (int i = 0; i < 8; ++i) { sm += red[i]; sa += red[8 + i]; sd += red[16 + i]; }
    const float mix_mean  = sm / (8.f * 512.f * 512.f);
    const float abs_mean  = sa / (8.f * 3.f * 512.f * 512.f);
    const float disc_mean = sd / (8.f * 62.f * 62.f);
    out[0] = 0.5f * (mix_mean + 100.f * abs_mean + disc_mean);
  }
}

extern "C" void kernel_launch(void* const* d_in, const int* in_sizes, int n_in,
                              void* d_out, int out_size, void* d_ws, size_t ws_size,
                              hipStream_t stream) {
  const float* x    = (const float*)d_in[0];
  const float* y    = (const float*)d_in[1];
  const float* disc = (const float*)d_in[2];
  // d_in[3] = g_masks (unused: weights recomputed on device)
  float* partials = (float*)d_ws;   // 2048*3 floats, fully overwritten each call
  dim3 grid(16, 16, 8);
  msssim_fused_kernel<<<grid, NT, 0, stream>>>(x, y, disc, partials);
  msssim_final_kernel<<<1, 512, 0, stream>>>(partials, (float*)d_out);
}